// Round 7
// baseline (112.712 us; speedup 1.0000x reference)
//
#include <hip/hip_runtime.h>
#include <math.h>

// SSIM on MI355X, round 7: long-lived single-wave blocks + software-pipelined
// global loads. Each 64-lane wave owns a 58-col strip and loops over 8 y-steps
// (4 output rows each); iteration i prefetches iteration i+1's 20 rows into a
// second register buffer before computing, hiding HBM latency inside the wave.
// Vertical 7-tap in registers -> private 5KB LDS -> horizontal 7-tap + SSIM.
// No __syncthreads anywhere; one partial store per block.

#define WI 320
#define HI 320
#define NI 64
#define TWO 58                  // output cols per x-tile (64 loaded incl. halo)
#define GXD 6                   // ceil(320/58); last tile has 30 valid cols
#define RPB 32                  // output rows per block
#define ITERS 8                 // RPB/4
#define GYD 10                  // 320/RPB
#define NBLK (GXD * GYD * NI)   // 3840
#define NPIX ((double)NI * WI * HI)

typedef float v4 __attribute__((ext_vector_type(4)));

struct W7 { float w[7]; };

// Issue 20 coalesced guarded loads for one 4-row strip (input rows ybase..+9).
__device__ __forceinline__ void issue_loads(
    const float* __restrict__ Xn, const float* __restrict__ Yn,
    int gx, bool xok, int ybase, float (&xr)[10], float (&yr)[10])
{
#pragma unroll
    for (int j = 0; j < 10; ++j) {
        const int gy  = ybase + j;
        const bool ok = xok && ((unsigned)gy < (unsigned)HI);
        float xv = 0.f, yv = 0.f;
        if (ok) { const int idx = gy * WI + gx; xv = Xn[idx]; yv = Yn[idx]; }
        xr[j] = xv; yr[j] = yv;
    }
}

// One 58x4 strip from a loaded 10-row register window: vertical 7-tap ->
// LDS -> horizontal 7-tap + SSIM. Returns this lane's masked partial sum.
__device__ __forceinline__ float compute_strip(
    const W7& wv, float* __restrict__ vb,
    const float (&xr)[10], const float (&yr)[10], int lane, int maxc)
{
    // ---- vertical 7-tap, 5 channels x 4 output rows, in registers ----
    float acc[5][4];
#pragma unroll
    for (int ch = 0; ch < 5; ++ch)
#pragma unroll
        for (int r = 0; r < 4; ++r) acc[ch][r] = 0.f;
#pragma unroll
    for (int j = 0; j < 10; ++j) {
        const float xv = xr[j], yv = yr[j];
        const float pxx = xv * xv, pyy = yv * yv, pxy = xv * yv;
#pragma unroll
        for (int r = 0; r < 4; ++r) {
            const int d = j - r;                 // compile-time predicate
            if (d >= 0 && d < 7) {
                const float w = wv.w[d];
                acc[0][r] += w * xv;
                acc[1][r] += w * yv;
                acc[2][r] += w * pxx;
                acc[3][r] += w * pyy;
                acc[4][r] += w * pxy;
            }
        }
    }
    // col = lane; 2 lanes/bank aliasing is free on gfx950.
#pragma unroll
    for (int ch = 0; ch < 5; ++ch)
#pragma unroll
        for (int r = 0; r < 4; ++r)
            vb[ch * 256 + r * 64 + lane] = acc[ch][r];

    __builtin_amdgcn_wave_barrier();   // wave-synchronous; lgkmcnt orders data

    // ---- horizontal 7-tap + SSIM. lane -> (row, 4 consecutive out cols) ----
    const int row = lane >> 4;
    const int xg  = (lane & 15) << 2;            // 0,4,...,60
    const float C1 = 0.0004f, C2 = 0.0036f, COVN = 49.f / 48.f;

    float m[4][5];
#pragma unroll
    for (int j = 0; j < 4; ++j)
#pragma unroll
        for (int ch = 0; ch < 5; ++ch) m[j][ch] = 0.f;
#pragma unroll
    for (int ch = 0; ch < 5; ++ch) {
        const v4* p = (const v4*)&vb[ch * 256 + row * 64 + xg];
        v4 a = p[0], b = p[1], c = p[2];         // 12 cols (pad covers tail)
        float f[12] = {a.x,a.y,a.z,a.w, b.x,b.y,b.z,b.w, c.x,c.y,c.z,c.w};
#pragma unroll
        for (int j = 0; j < 4; ++j) {
            float s = 0.f;
#pragma unroll
            for (int d = 0; d < 7; ++d) s += wv.w[d] * f[j + d];
            m[j][ch] = s;
        }
    }
    float lsum = 0.f;
#pragma unroll
    for (int j = 0; j < 4; ++j) {
        const float mx = m[j][0], my = m[j][1];
        const float mxsq = mx * mx;
        const float mysq = my * my;
        const float mxy  = mx * my;
        const float vx   = (m[j][2] - mxsq) * COVN;
        const float vy   = (m[j][3] - mysq) * COVN;
        const float vxy  = (m[j][4] - mxy)  * COVN;
        const float num  = (2.f * mxy + C1) * (2.f * vxy + C2);
        const float den  = (mxsq + mysq + C1) * (vx + vy + C2);
        lsum += (xg + j < maxc) ? num * __builtin_amdgcn_rcpf(den) : 0.f;
    }
    return lsum;
}

__global__ __launch_bounds__(64) void ssim_kernel(
    const float* __restrict__ X, const float* __restrict__ Y,
    W7 wv, float* __restrict__ partial)
{
    __shared__ __align__(16) float vbuf[5 * 4 * 64 + 16];  // 5.2 KB, +pad for b128 tail

    const int lane = threadIdx.x;
    const int x0   = blockIdx.x * TWO;
    const int y0   = blockIdx.y * RPB;
    const float* __restrict__ Xn = X + (size_t)blockIdx.z * (WI * HI);
    const float* __restrict__ Yn = Y + (size_t)blockIdx.z * (WI * HI);

    const int  gx   = x0 + lane - 3;
    const bool xok  = (unsigned)gx < (unsigned)WI;   // covers both x edges
    const int  maxc = (x0 + TWO <= WI) ? TWO : (WI - x0);

    float ax[10], ay[10], bx[10], by[10];
    issue_loads(Xn, Yn, gx, xok, y0 - 3, ax, ay);

    float lsum = 0.f;
#pragma unroll 1
    for (int ii = 0; ii < ITERS; ii += 2) {
        // prefetch strip ii+1 while computing strip ii (and vice versa)
        issue_loads(Xn, Yn, gx, xok, y0 + 4 * (ii + 1) - 3, bx, by);
        lsum += compute_strip(wv, vbuf, ax, ay, lane, maxc);
        if (ii + 2 < ITERS)
            issue_loads(Xn, Yn, gx, xok, y0 + 4 * (ii + 2) - 3, ax, ay);
        lsum += compute_strip(wv, vbuf, bx, by, lane, maxc);
    }

    // ---- wave reduction -> per-block partial ----
#pragma unroll
    for (int off = 32; off > 0; off >>= 1)
        lsum += __shfl_down(lsum, off, 64);
    if (lane == 0) {
        const int bid = (blockIdx.z * GYD + blockIdx.y) * GXD + blockIdx.x;
        partial[bid] = lsum;
    }
}

__global__ __launch_bounds__(256) void ssim_finalize(
    const float* __restrict__ partial, float* __restrict__ out)
{
    __shared__ double ws[4];
    const int tid = threadIdx.x;
    double s = 0.0;
    for (int i = tid; i < NBLK; i += 256) s += (double)partial[i];
#pragma unroll
    for (int off = 32; off > 0; off >>= 1)
        s += __shfl_down(s, off, 64);
    if ((tid & 63) == 0) ws[tid >> 6] = s;
    __syncthreads();
    if (tid == 0)
        out[0] = (float)(1.0 - ((ws[0] + ws[1]) + (ws[2] + ws[3])) / NPIX);
}

extern "C" void kernel_launch(void* const* d_in, const int* in_sizes, int n_in,
                              void* d_out, int out_size, void* d_ws, size_t ws_size,
                              hipStream_t stream) {
    const float* X = (const float*)d_in[0];
    const float* Y = (const float*)d_in[1];
    // Exact 1D Gaussian weights in fp64 (7x7 window = outer product).
    W7 wv;
    {
        double g[7], s = 0.0;
        for (int i = 0; i < 7; ++i) {
            double x = (double)(i - 3);
            g[i] = exp(-(x * x) / (2.0 * 1.5 * 1.5));
            s += g[i];
        }
        for (int i = 0; i < 7; ++i) wv.w[i] = (float)(g[i] / s);
    }

    float* partial = (float*)d_ws;   // 3840 floats, fully written every launch

    dim3 grid(GXD, GYD, NI);
    ssim_kernel<<<grid, 64, 0, stream>>>(X, Y, wv, partial);
    ssim_finalize<<<1, 256, 0, stream>>>(partial, (float*)d_out);
}

// Round 8
// 110.832 us; speedup vs baseline: 1.0170x; 1.0170x over previous
//
#include <hip/hip_runtime.h>
#include <math.h>

// SSIM on MI355X, round 8: rolling-window separable conv with (X,Y) packed as
// float2 (targets v_pk_fma_f32). Each wave owns a 58-col x 32-row strip and
// walks it in four 8-row iterations: 8 new rows loaded per iteration into a
// rolling 14-row float2 register window (every input row loaded ONCE), packed
// vertical 7-tap -> per-wave LDS slabs (bank-balanced strides) -> horizontal
// 7-tap + SSIM (8 outputs/lane). 2 waves/block, no __syncthreads.

#define WI 320
#define HI 320
#define NI 64
#define TWO 58                  // output cols per x-tile (64 loaded incl halo)
#define GXD 6
#define SROWS 32                // output rows per wave strip
#define ITERS 4                 // 8-row iterations per strip
#define WPB 2                   // waves per block
#define RPB (WPB * SROWS)       // 64 rows per block
#define GYD (HI / RPB)          // 5
#define NBLK (GXD * GYD * NI)   // 1920
#define NPART (NBLK * WPB)      // 3840 partials
#define NPIX ((double)NI * WI * HI)

// per-wave LDS slab layout (dword offsets). mu/sq rows: 68 float2 pairs,
// stride 136 dwords (bank-balanced, 16B-aligned). xy rows: stride 68.
#define MU_OFF 0
#define SQ_OFF 1088
#define XY_OFF 2176
#define WAVE_LDS 2752           // 2720 used + pad for b128 tail overrun

typedef float v2 __attribute__((ext_vector_type(2)));
typedef float v4 __attribute__((ext_vector_type(4)));

struct W7 { float w[7]; };

// extract pair p / scalar p from a v4-loaded register block (p constant after unroll)
__device__ __forceinline__ v2 pget(const v4* t, int p) {
    v4 q = t[p >> 1];
    return (p & 1) ? (v2){q.z, q.w} : (v2){q.x, q.y};
}
__device__ __forceinline__ float sget(const v4* t, int p) {
    v4 q = t[p >> 2];
    switch (p & 3) { case 0: return q.x; case 1: return q.y; case 2: return q.z; default: return q.w; }
}

__global__ __launch_bounds__(WPB * 64) void ssim_kernel(
    const float* __restrict__ X, const float* __restrict__ Y,
    W7 wv, float* __restrict__ partial)
{
    __shared__ __align__(16) float lds_all[WPB * WAVE_LDS + 16];

    const int tid  = threadIdx.x;
    const int lane = tid & 63;
    const int wid  = tid >> 6;
    float* lds = lds_all + wid * WAVE_LDS;

    const int x0 = blockIdx.x * TWO;
    const int y0 = blockIdx.y * RPB + wid * SROWS;
    const float* __restrict__ Xn = X + (size_t)blockIdx.z * (WI * HI);
    const float* __restrict__ Yn = Y + (size_t)blockIdx.z * (WI * HI);

    const int  gx   = x0 + lane - 3;                 // lane = loaded col
    const bool xok  = (unsigned)gx < (unsigned)WI;
    const int  gxc  = min(max(gx, 0), WI - 1);       // clamped (always-safe addr)
    const int  maxc = min(TWO, WI - x0);

    // rolling 14-row window of (X,Y) pairs; prime rows y0-3 .. y0+2
    v2 win[14];
#pragma unroll
    for (int k = 0; k < 6; ++k) {
        const int gy  = y0 - 3 + k;
        const bool ok = xok && ((unsigned)gy < (unsigned)HI);
        const int gyc = min(max(gy, 0), HI - 1);
        const size_t idx = (size_t)gyc * WI + gxc;
        v2 t; t.x = Xn[idx]; t.y = Yn[idx];
        win[k] = ok ? t : (v2){0.f, 0.f};
    }

    const float C1 = 0.0004f, C2 = 0.0036f, COVN = 49.f / 48.f;
    const int row = lane >> 3;      // hconv: output row 0..7
    const int g   = lane & 7;       // hconv: col group (8 cols)

    float lsum = 0.f;
#pragma unroll 1
    for (int it = 0; it < ITERS; ++it) {
        const int base_row = y0 + it * 8;

        // ---- load 8 NEW rows (base_row+3 .. base_row+10) into win[6..13] ----
#pragma unroll
        for (int k = 0; k < 8; ++k) {
            const int gy  = base_row + 3 + k;
            const bool ok = xok && ((unsigned)gy < (unsigned)HI);
            const int gyc = min(max(gy, 0), HI - 1);
            const size_t idx = (size_t)gyc * WI + gxc;
            v2 t; t.x = Xn[idx]; t.y = Yn[idx];
            win[6 + k] = ok ? t : (v2){0.f, 0.f};
        }

        // ---- vertical 7-tap, packed: mu2=(mux,muy), sq2=(sxx,syy), xy ----
        v2 amu[8], asq[8]; float axy[8];
#pragma unroll
        for (int r = 0; r < 8; ++r) { amu[r] = (v2){0.f,0.f}; asq[r] = (v2){0.f,0.f}; axy[r] = 0.f; }
#pragma unroll
        for (int k = 0; k < 14; ++k) {
            const v2 v   = win[k];
            const v2 sq  = v * v;
            const float pxy = v.x * v.y;
#pragma unroll
            for (int r = 0; r < 8; ++r) {
                const int d = k - r;                 // compile-time predicate
                if (d >= 0 && d < 7) {
                    const float w = wv.w[d];
                    amu[r] += w * v;
                    asq[r] += w * sq;
                    axy[r] += w * pxy;
                }
            }
        }

        // ---- LDS writes: col = lane; strides bank-balanced ----
#pragma unroll
        for (int r = 0; r < 8; ++r) {
            *(v2*)&lds[MU_OFF + r * 136 + 2 * lane] = amu[r];
            *(v2*)&lds[SQ_OFF + r * 136 + 2 * lane] = asq[r];
            lds[XY_OFF + r * 68 + lane] = axy[r];
        }
        __builtin_amdgcn_wave_barrier();   // wave-synchronous; DS in-order + lgkmcnt

        // ---- horizontal 7-tap: lane -> (row, cols 8g..8g+7) ----
        // LDS col c holds image col x0+c-3; output t needs cols t..t+6.
        v2 mmu[8], msq[8]; float mxy[8];
#pragma unroll
        for (int j = 0; j < 8; ++j) { mmu[j] = (v2){0.f,0.f}; msq[j] = (v2){0.f,0.f}; mxy[j] = 0.f; }
        {
            v4 t[8];
#pragma unroll
            for (int q = 0; q < 8; ++q)
                t[q] = *(const v4*)&lds[MU_OFF + row * 136 + 16 * g + 4 * q];
#pragma unroll
            for (int j = 0; j < 8; ++j)
#pragma unroll
                for (int d = 0; d < 7; ++d)
                    mmu[j] += wv.w[d] * pget(t, j + d);
        }
        {
            v4 t[8];
#pragma unroll
            for (int q = 0; q < 8; ++q)
                t[q] = *(const v4*)&lds[SQ_OFF + row * 136 + 16 * g + 4 * q];
#pragma unroll
            for (int j = 0; j < 8; ++j)
#pragma unroll
                for (int d = 0; d < 7; ++d)
                    msq[j] += wv.w[d] * pget(t, j + d);
        }
        {
            v4 t[4];
#pragma unroll
            for (int q = 0; q < 4; ++q)
                t[q] = *(const v4*)&lds[XY_OFF + row * 68 + 8 * g + 4 * q];
#pragma unroll
            for (int j = 0; j < 8; ++j)
#pragma unroll
                for (int d = 0; d < 7; ++d)
                    mxy[j] += wv.w[d] * sget(t, j + d);
        }

        // ---- SSIM map + masked accumulate ----
#pragma unroll
        for (int j = 0; j < 8; ++j) {
            const v2 mu    = mmu[j];
            const v2 musq  = mu * mu;                     // (mx^2, my^2)
            const float pm = mu.x * mu.y;                 // mx*my
            const v2 sig   = (msq[j] - musq) * COVN;      // (vx, vy)
            const float vxy = (mxy[j] - pm) * COVN;
            const float num = (2.f * pm + C1) * (2.f * vxy + C2);
            const float den = (musq.x + musq.y + C1) * (sig.x + sig.y + C2);
            lsum += (8 * g + j < maxc) ? num * __builtin_amdgcn_rcpf(den) : 0.f;
        }

        // ---- roll the window down 8 rows ----
#pragma unroll
        for (int k = 0; k < 6; ++k) win[k] = win[k + 8];
    }

    // ---- wave reduction -> per-wave partial ----
#pragma unroll
    for (int off = 32; off > 0; off >>= 1)
        lsum += __shfl_down(lsum, off, 64);
    if (lane == 0) {
        const int bid = ((blockIdx.z * GYD + blockIdx.y) * GXD + blockIdx.x) * WPB + wid;
        partial[bid] = lsum;
    }
}

__global__ __launch_bounds__(256) void ssim_finalize(
    const float* __restrict__ partial, float* __restrict__ out)
{
    __shared__ double ws[4];
    const int tid = threadIdx.x;
    double s = 0.0;
    for (int i = tid; i < NPART; i += 256) s += (double)partial[i];
#pragma unroll
    for (int off = 32; off > 0; off >>= 1)
        s += __shfl_down(s, off, 64);
    if ((tid & 63) == 0) ws[tid >> 6] = s;
    __syncthreads();
    if (tid == 0)
        out[0] = (float)(1.0 - ((ws[0] + ws[1]) + (ws[2] + ws[3])) / NPIX);
}

extern "C" void kernel_launch(void* const* d_in, const int* in_sizes, int n_in,
                              void* d_out, int out_size, void* d_ws, size_t ws_size,
                              hipStream_t stream) {
    const float* X = (const float*)d_in[0];
    const float* Y = (const float*)d_in[1];
    // Exact 1D Gaussian weights in fp64 (7x7 window = outer product).
    W7 wv;
    {
        double gk[7], s = 0.0;
        for (int i = 0; i < 7; ++i) {
            double x = (double)(i - 3);
            gk[i] = exp(-(x * x) / (2.0 * 1.5 * 1.5));
            s += gk[i];
        }
        for (int i = 0; i < 7; ++i) wv.w[i] = (float)(gk[i] / s);
    }

    float* partial = (float*)d_ws;   // 3840 floats, fully written every launch

    dim3 grid(GXD, GYD, NI);         // 6 x 5 x 64 = 1920 blocks, 128 thr
    ssim_kernel<<<grid, WPB * 64, 0, stream>>>(X, Y, wv, partial);
    ssim_finalize<<<1, 256, 0, stream>>>(partial, (float*)d_out);
}